// Round 4
// baseline (551.505 us; speedup 1.0000x reference)
//
#include <hip/hip_runtime.h>

// JBF block: M = 2*16*128*128 = 524288 voxels, 125-float (500 B) dom/gui record each.
// v5: register-pressure fix on top of v3/v4's 8 KB phased staging.
//  - R2: __launch_bounds__(64,4) -> 64 VGPR, scratch spill disaster (WRITE 880 MB).
//  - R3: plain __launch_bounds__(64) -> 200 VGPR (hoisted staging addresses),
//    2 waves/SIMD, occupancy 10.7%, 168 us — occupancy never materialized.
//  - v5: hard cap via amdgpu_num_vgpr(128) -> 4 waves/SIMD = 16 waves/CU, forcing
//    address rematerialization instead of hoarding (live set ~80 regs, no spill).
//  - Swizzle upgraded to 4-dword granule so conv reads are ds_read_b128:
//    logical float c of record v sits at slot (c&3) | (((c>>2)^qv)<<2), qv=(v&31)>>2.
//    Involution; 16B groups stay contiguous; lane quads fan out across the 8
//    16B-groups -> uniform 4 accesses/bank (b128 minimum). Write side stays
//    gl_lds-linear; qv for staging instr k reduces to (k&15)>>1 (lane-independent,
//    compile-time). Accumulation order still ascending-f -> numerics identical.
// f=124 (odd float out of 4x32) only feeds acc[26]; per-lane register load.

#define VPB 64          // voxels per block == block size (1 wave)
#define REC 125         // floats per record

#define GAS(p) ((const __attribute__((address_space(1))) float*)(p))
#define LAS(p) ((__attribute__((address_space(3))) float*)(p))

// Stage floats [F0, F0+32) of all 64 records into lds[64][32] (linear dwords).
// gl_lds instr k writes lane l -> LDS dword k*64+l = record v=2k+(l>>5), slot l&31.
// Source float for slot s of record v: F0 + (s&3) + (((s>>2) ^ qv)<<2).
template <int F0>
__device__ __forceinline__ void stage32(const float* __restrict__ src, int m0,
                                        float* lds, int lane)
{
    const int half = lane >> 5;        // which record of the pair this lane serves
    const int s3   = lane & 3;
    const int sh   = (lane & 31) >> 2;
    const float* base = src + (size_t)(m0 + half) * REC + F0;
#pragma unroll
    for (int k = 0; k < 32; ++k) {
        const int qk = (k & 15) >> 1;  // = ((2k+half)&31)>>2 (half can't carry)
        int fo = s3 | ((sh ^ qk) << 2);
        if (F0 == 96) fo = fo <= 27 ? fo : 27;  // pad slots: dup load, never read
        __builtin_amdgcn_global_load_lds(GAS(base + (size_t)(2 * k) * REC + fo),
                                         LAS(lds + k * 64), 4, 0, 0);
    }
}

// Accumulate conv taps for floats [F0, F0+4*QMAX). Lane reads its own record
// (row `lane`) as QMAX ds_read_b128: logical floats 4q..4q+3 live at dwords
// rb + ((q^qx)<<2) .. +3  (16B-aligned).
template <int F0>
__device__ __forceinline__ void conv_part(const float* __restrict__ sbuf, int lane,
                                          const float* __restrict__ w, float* acc)
{
    const int qx = (lane & 31) >> 2;
    const int rb = lane * 32;
    const int QMAX = (F0 == 96) ? 7 : 8;   // F0=96 covers floats 96..123 (f=124 in reg)
#pragma unroll
    for (int q = 0; q < 8; ++q) {
        if (q >= QMAX) break;
        const float4 vv = *(const float4*)&sbuf[rb + ((q ^ qx) << 2)];
        const float vals[4] = {vv.x, vv.y, vv.z, vv.w};
#pragma unroll
        for (int t = 0; t < 4; ++t) {
            const int f = F0 + 4 * q + t;
            const float v = vals[t];
            const int z  = f / 25;
            const int r  = (f % 25) / 5;
            const int c5 = f % 5;
#pragma unroll
            for (int i = 0; i < 3; ++i) {
                const int a = z - i; if (a < 0 || a > 2) continue;
#pragma unroll
                for (int j = 0; j < 3; ++j) {
                    const int b = r - j; if (b < 0 || b > 2) continue;
#pragma unroll
                    for (int l = 0; l < 3; ++l) {
                        const int cc = c5 - l; if (cc < 0 || cc > 2) continue;
                        acc[(i * 3 + j) * 3 + l] =
                            fmaf(v, w[(a * 3 + b) * 3 + cc],
                                 acc[(i * 3 + j) * 3 + l]);
                    }
                }
            }
        }
    }
}

__global__ __launch_bounds__(64)
__attribute__((amdgpu_num_vgpr(128)))
void jbf_kernel(
    const float* __restrict__ x,      // [2,1,18,128,128]
    const float* __restrict__ dom,    // [M,125]
    const float* __restrict__ gui,    // [M,125]
    const float* __restrict__ dom_w,  // [27]
    const float* __restrict__ dom_b,  // [1]
    const float* __restrict__ rng_w,  // [27]
    const float* __restrict__ rng_b,  // [1]
    float* __restrict__ out)          // [M]
{
    __shared__ __align__(16) float sm[VPB * 32];   // 8192 B
    const int lane = threadIdx.x;
    const int m0   = blockIdx.x * VPB;
    const int m    = m0 + lane;

    const float bd = dom_b[0], br = rng_b[0];

    float dkv[27], acc[27];

    // One code instance for both convs (I-cache): p=0 dom->dkv, p=1 gui->acc.
#pragma unroll 1
    for (int p = 0; p < 2; ++p) {
        const float* __restrict__ src  = p ? gui : dom;
        const float* __restrict__ wsrc = p ? rng_w : dom_w;
        // force conv weights into SGPRs (uniform) so they don't eat the VGPR cap
        float w[27];
#pragma unroll
        for (int i = 0; i < 27; ++i)
            w[i] = __uint_as_float(
                __builtin_amdgcn_readfirstlane(__float_as_uint(wsrc[i])));
#pragma unroll
        for (int i = 0; i < 27; ++i) acc[i] = 0.f;

        // f=124 never tiles into the 4x32 phases; only feeds acc[26]
        // ((z,r,c)=(4,4,4) -> single valid output tap (2,2,2)).
        const float v124 = src[(size_t)m * REC + 124];

        stage32<0>(src, m0, sm, lane);
        __syncthreads();                       // drains gl_lds (vmcnt) + visibility
        conv_part<0>(sm, lane, w, acc);
        __syncthreads();                       // reads done before restage

        stage32<32>(src, m0, sm, lane);
        __syncthreads();
        conv_part<32>(sm, lane, w, acc);
        __syncthreads();

        stage32<64>(src, m0, sm, lane);
        __syncthreads();
        conv_part<64>(sm, lane, w, acc);
        __syncthreads();

        stage32<96>(src, m0, sm, lane);
        __syncthreads();
        conv_part<96>(sm, lane, w, acc);
        __syncthreads();

        // f=124 term last, preserving original ascending-f accumulation order
        acc[26] = fmaf(v124, w[26], acc[26]);

        if (p == 0) {
#pragma unroll
            for (int i = 0; i < 27; ++i) dkv[i] = acc[i];
        }
    }
    // here: dkv = dom conv, acc = gui conv

    // ---- epilogue: weights * x-neighborhood, normalize (unchanged) ----
    // m = ((b*16 + dz)*128 + h)*128 + w
    const int w_ = m & 127;
    const int h_ = (m >> 7) & 127;
    const int dz = (m >> 14) & 15;
    const int b_ = m >> 18;

    float num = 0.f, den = 0.f;
#pragma unroll
    for (int i = 0; i < 3; ++i) {
        const int zz = b_ * 18 + dz + i;   // depth always in range
#pragma unroll
        for (int j = 0; j < 3; ++j) {
            const int hh = h_ - 1 + j;
            const bool okh = (unsigned)hh < 128u;
#pragma unroll
            for (int l = 0; l < 3; ++l) {
                const int ww = w_ - 1 + l;
                const bool ok = okh && ((unsigned)ww < 128u);
                const float xv = ok ? x[((size_t)zz * 128 + hh) * 128 + ww] : 0.f;
                const float wv = fmaxf(dkv[(i * 3 + j) * 3 + l] + bd, 0.f) *
                                 fmaxf(acc[(i * 3 + j) * 3 + l] + br, 0.f) + 1e-10f;
                den += wv;
                num = fmaf(wv, xv, num);
            }
        }
    }
    out[m] = num / den;
}

extern "C" void kernel_launch(void* const* d_in, const int* in_sizes, int n_in,
                              void* d_out, int out_size, void* d_ws, size_t ws_size,
                              hipStream_t stream) {
    const float* x     = (const float*)d_in[0];
    const float* dom   = (const float*)d_in[1];
    const float* gui   = (const float*)d_in[2];
    const float* dom_w = (const float*)d_in[3];
    const float* dom_b = (const float*)d_in[4];
    const float* rng_w = (const float*)d_in[5];
    const float* rng_b = (const float*)d_in[6];
    float* outp = (float*)d_out;

    const int M = in_sizes[1] / REC;      // 524288
    const int grid = M / VPB;             // 8192 blocks
    jbf_kernel<<<grid, VPB, 0, stream>>>(x, dom, gui, dom_w, dom_b,
                                         rng_w, rng_b, outp);
}